// Round 9
// baseline (411.737 us; speedup 1.0000x reference)
//
#include <hip/hip_runtime.h>
#include <math.h>

// CRF log-likelihood, B=512, S=512, T=128.
// ROUND 18: ONE BLOCK PER CU, 8 WAVES, EACH WAVE DOES 2 BATCHES.
// R17 null confirmed the 968 cyc/step wall is structural: two independent
// blocks/CU don't anti-phase, so each block's barrier+LDS chain is only
// half-hidden. Fix: merge the CU's two batches into ONE 512-thr block.
//  - 8 waves = 2/SIMD (R13/R16's proven occupancy), one barrier domain.
//  - wave w owns cols 16w..16w+15 of BOTH batches; lane: 1 col x 32 rows
//    -> E = 32 floats (R15's proven layout, 0 bank conflicts), shared by
//    both batches (the R14 trap avoided).
//  - one barrier per step advances BOTH batches: same 511 barriers, but
//    each interval has 2x deterministic intra-wave ILP (B's reads/FMAs
//    fill A's ds_read latency) and per-step overhead (norm, loop, addr)
//    is paid once for two batches.
// Numerics per batch = R15 tree + R16 norm-every-4 (both passed,
// absmax 0.0); cols dup x4 over rg -> exact 0.25f fix.
// Kept: lgkm-only barrier (prefetch stays in flight), xor-swizzled p
// buffers, linear-domain recursion + exact double Ld accounting.

#define T 128
#define SLEN 512
#define BATCH 512

typedef float v2f __attribute__((ext_vector_type(2)));

static __device__ __forceinline__ float dpp_xor1(float x) {
    // quad_perm [1,0,3,2] == lane ^ 1
    return __int_as_float(__builtin_amdgcn_update_dpp(
        0, __float_as_int(x), 0xB1, 0xF, 0xF, true));
}
static __device__ __forceinline__ float dpp_xor2(float x) {
    // quad_perm [2,3,0,1] == lane ^ 2
    return __int_as_float(__builtin_amdgcn_update_dpp(
        0, __float_as_int(x), 0x4E, 0xF, 0xF, true));
}
static __device__ __forceinline__ void lgkm_barrier() {
    // LDS-writes-drained barrier that leaves vmcnt (global prefetch) alone.
    asm volatile("s_waitcnt lgkmcnt(0)\n\ts_barrier" ::: "memory");
}
// Bank swizzle for the 128-word p buffer: 4-word groups xor'd by (j>>5).
static __device__ __forceinline__ int pslot(int j) {
    return j ^ (((j >> 5) & 3) << 2);
}

__global__ __launch_bounds__(512, 2) void fwd_kernel(
    const float* __restrict__ em, const int* __restrict__ tags,
    const int* __restrict__ mask, const float* __restrict__ startT,
    const float* __restrict__ endT, const float* __restrict__ trans,
    float* __restrict__ ws)
{
    const int tid  = threadIdx.x;      // 0..511
    const int lane = tid & 63;
    const int w    = tid >> 6;         // wave 0..7: cols 16w..16w+15
    const int rg   = lane & 3;         // row group: rows 32rg..32rg+31
    const int cg   = lane >> 2;        // col within wave: 0..15
    const int bA   = 2 * blockIdx.x;
    const int bB   = bA + 1;
    const int mycol = 16 * w + cg;     // this lane's column (dup x4 over rg)

    const float* embA = em + (size_t)bA * SLEN * T;
    const float* embB = em + (size_t)bB * SLEN * T;
    const int*   mkA  = mask + (size_t)bA * SLEN;
    const int*   mkB  = mask + (size_t)bB * SLEN;

    __shared__ __align__(16) float p_lds[2][2][T];   // [batch][buf][slot] 2KB
    __shared__ float reds[2][8], redn[2][8];
    __shared__ int   redc[2][8];

    // Read slots (R15-verified conflict-free): instr k2 reads rows
    // 32rg+4k2..+3 at swizzled slot 32rg + 4*(k2^rg).
    int rslot[8];
#pragma unroll
    for (int k2 = 0; k2 < 8; ++k2)
        rslot[k2] = 32 * rg + 4 * (k2 ^ rg);
    const int wslot = pslot(mycol);

    // E fragment (shared by both batches): Elo[k2] = (e^trans[r][col],
    // e^trans[r+1][col]), Ehi[k2] = rows (r+2, r+3); r = 32rg + 4k2.
    // 16 v2f = 32 regs.
    v2f Elo[8], Ehi[8];
#pragma unroll
    for (int k2 = 0; k2 < 8; ++k2) {
        const float* tp = trans + (32 * rg + 4 * k2) * T + mycol;
        Elo[k2] = (v2f){ __expf(tp[0 * T]), __expf(tp[1 * T]) };
        Ehi[k2] = (v2f){ __expf(tp[2 * T]), __expf(tp[3 * T]) };
    }

    // alpha_0 in linear domain; step 1 reads buffer 1. Writers rg==0
    // (16 distinct banks per wave).
    float ppA = __expf(startT[mycol] + embA[mycol]);
    float ppB = __expf(startT[mycol] + embB[mycol]);
    if (rg == 0) { p_lds[0][1][wslot] = ppA; p_lds[1][1][wslot] = ppB; }
    double LdA = 0.0, LdB = 0.0;

    // 4-deep emission/mask prefetch per batch; exp applied off-chain.
    float emvA[4], emnA[4], emvB[4], emnB[4];
    int   mkvA[4], mknA[4], mkvB[4], mknB[4];
#pragma unroll
    for (int k = 0; k < 4; ++k) {
        emvA[k] = __expf(embA[(1 + k) * T + mycol]);
        emvB[k] = __expf(embB[(1 + k) * T + mycol]);
        mkvA[k] = mkA[1 + k];
        mkvB[k] = mkB[1 + k];
    }
    lgkm_barrier();

    for (int s0 = 1; s0 < SLEN; s0 += 4) {
#pragma unroll
        for (int k = 0; k < 4; ++k) {
            int ss = s0 + 4 + k; ss = (ss < SLEN) ? ss : (SLEN - 1);  // uniform
            emnA[k] = embA[ss * T + mycol];
            emnB[k] = embB[ss * T + mycol];
            mknA[k] = mkA[ss];
            mknB[k] = mkB[ss];
        }
#pragma unroll
        for (int k = 0; k < 4; ++k) {
            const int s = s0 + k;
            if (s < SLEN) {                       // uniform guard (511 steps)
                const int cur = (1 + k) & 1;      // == s&1, compile-time
                // Normalize only on k==0 (s = 1 mod 4), both batches.
                float ccA = 1.0f, ccB = 1.0f;
                if (k == 0) {
                    const float srefA = fmaxf(p_lds[0][cur][0], 1e-30f);
                    const float srefB = fmaxf(p_lds[1][cur][0], 1e-30f);
                    ccA = __builtin_amdgcn_rcpf(srefA);
                    ccB = __builtin_amdgcn_rcpf(srefB);
                    LdA += (double)__logf(srefA); // exact accounting
                    LdB += (double)__logf(srefB);
                }

                // 8 b128 reads per batch (conflict-free; cg lanes bcast).
                v2f pkA0[8], pkA1[8], pkB0[8], pkB1[8];
#pragma unroll
                for (int k2 = 0; k2 < 8; ++k2) {
                    const float4 pa = *(const float4*)&p_lds[0][cur][rslot[k2]];
                    const float4 pb = *(const float4*)&p_lds[1][cur][rslot[k2]];
                    pkA0[k2] = (v2f){ pa.x, pa.y }; pkA1[k2] = (v2f){ pa.z, pa.w };
                    pkB0[k2] = (v2f){ pb.x, pb.y }; pkB1[k2] = (v2f){ pb.z, pb.w };
                }
                // 32 pk_fma in 4 independent depth-8 chains (2 batches x E/O).
                v2f aAe = pkA0[0] * Elo[0], aAo = pkA1[0] * Ehi[0];
                v2f aBe = pkB0[0] * Elo[0], aBo = pkB1[0] * Ehi[0];
#pragma unroll
                for (int k2 = 1; k2 < 8; ++k2) {
                    aAe = __builtin_elementwise_fma(pkA0[k2], Elo[k2], aAe);
                    aAo = __builtin_elementwise_fma(pkA1[k2], Ehi[k2], aAo);
                    aBe = __builtin_elementwise_fma(pkB0[k2], Elo[k2], aBe);
                    aBo = __builtin_elementwise_fma(pkB1[k2], Ehi[k2], aBo);
                }
                const v2f sAv = aAe + aAo, sBv = aBe + aBo;
                const float svA = sAv.x + sAv.y;
                const float svB = sBv.x + sBv.y;

                // 2-stage DPP butterfly over the 4 rg lanes (dup x4).
                float tA = svA + dpp_xor1(svA);
                tA = tA + dpp_xor2(tA);
                float tB = svB + dpp_xor1(svB);
                tB = tB + dpp_xor2(tB);

                // Linear-domain update; mask=0 keeps alpha (scaled on
                // normalize steps only).
                float pnA, pmA, pnB, pmB;
                if (k == 0) { pnA = tA * (emvA[k] * ccA); pmA = ppA * ccA;
                              pnB = tB * (emvB[k] * ccB); pmB = ppB * ccB; }
                else        { pnA = tA * emvA[k];         pmA = ppA;
                              pnB = tB * emvB[k];         pmB = ppB;      }
                ppA = (mkvA[k] > 0) ? pnA : pmA;
                ppB = (mkvB[k] > 0) ? pnB : pmB;
                if (rg == 0) {
                    p_lds[0][cur ^ 1][wslot] = ppA;
                    p_lds[1][cur ^ 1][wslot] = ppB;
                }
                lgkm_barrier();                   // no vmcnt drain
            }
        }
#pragma unroll
        for (int k = 0; k < 4; ++k) {
            emvA[k] = __expf(emnA[k]); mkvA[k] = mknA[k];
            emvB[k] = __expf(emnB[k]); mkvB[k] = mknB[k];
        }
    }

    // ---- denominators: log(sum_j p_j e^endT_j) + Ld  (cols dup x4 over
    // rg -> exact 0.25f fix) ----
    const float eendv = __expf(endT[mycol]);
    float smA = ppA * eendv, smB = ppB * eendv;
#pragma unroll
    for (int off = 32; off; off >>= 1) {
        smA += __shfl_xor(smA, off);
        smB += __shfl_xor(smB, off);
    }
    if (lane == 0) { reds[0][w] = smA; reds[1][w] = smB; }

    // ---- numerators: 1 step per thread (512 threads cover s=0..511) ----
    const int* tgA = tags + (size_t)bA * SLEN;
    const int* tgB = tags + (size_t)bB * SLEN;
    float nvA = 0.f, nvB = 0.f; int cntA = 0, cntB = 0;
    {
        const int s = tid;
        const int mmA = mkA[s], mmB = mkB[s];
        cntA += (mmA != 0);
        cntB += (mmB != 0);
        if (s >= 1 && mmA > 0)
            nvA += trans[tgA[s - 1] * T + tgA[s]] + embA[s * T + tgA[s]];
        if (s >= 1 && mmB > 0)
            nvB += trans[tgB[s - 1] * T + tgB[s]] + embB[s * T + tgB[s]];
    }
#pragma unroll
    for (int off = 32; off; off >>= 1) {
        nvA += __shfl_xor(nvA, off); cntA += __shfl_xor(cntA, off);
        nvB += __shfl_xor(nvB, off); cntB += __shfl_xor(cntB, off);
    }
    if (lane == 0) { redn[0][w] = nvA; redc[0][w] = cntA;
                     redn[1][w] = nvB; redc[1][w] = cntB; }
    __syncthreads();
    if (tid == 0) {
        float ssA = 0.f, nsA = 0.f, ssB = 0.f, nsB = 0.f;
        int slA = 0, slB = 0;
#pragma unroll
        for (int i = 0; i < 8; ++i) {
            ssA += reds[0][i]; nsA += redn[0][i]; slA += redc[0][i];
            ssB += reds[1][i]; nsB += redn[1][i]; slB += redc[1][i];
        }
        const float denomA = __logf(0.25f * ssA) + (float)LdA;  // exact /4
        const float denomB = __logf(0.25f * ssB) + (float)LdB;
        const int tA0 = tgA[0], tAl = tgA[slA - 1];
        const int tB0 = tgB[0], tBl = tgB[slB - 1];
        ws[bA] = (startT[tA0] + embA[tA0] + endT[tAl] + nsA) - denomA;
        ws[bB] = (startT[tB0] + embB[tB0] + endT[tBl] + nsB) - denomB;
    }
}

__global__ __launch_bounds__(256) void reduce_kernel(
    const float* __restrict__ ws, float* __restrict__ out)
{
    const int t = threadIdx.x;          // one block of 256
    float local = 0.f;
    for (int i = t; i < BATCH; i += 256) local += ws[i];
    __shared__ float rf[256];
    rf[t] = local;
    __syncthreads();
    for (int off = 128; off > 0; off >>= 1) {
        if (t < off) rf[t] += rf[t + off];
        __syncthreads();
    }
    if (t == 0) out[0] = rf[0];
}

extern "C" void kernel_launch(void* const* d_in, const int* in_sizes, int n_in,
                              void* d_out, int out_size, void* d_ws, size_t ws_size,
                              hipStream_t stream)
{
    const float* emissions = (const float*)d_in[0];
    const int*   tags      = (const int*)d_in[1];
    const int*   mask      = (const int*)d_in[2];
    const float* startT    = (const float*)d_in[3];
    const float* endT      = (const float*)d_in[4];
    const float* trans     = (const float*)d_in[5];
    float* out = (float*)d_out;
    float* ws  = (float*)d_ws;          // BATCH floats of per-batch partials

    fwd_kernel<<<BATCH / 2, 512, 0, stream>>>(emissions, tags, mask, startT, endT, trans, ws);
    reduce_kernel<<<1, 256, 0, stream>>>(ws, out);
}

// Round 10
// 320.844 us; speedup vs baseline: 1.2833x; 1.2833x over previous
//
#include <hip/hip_runtime.h>
#include <math.h>

// CRF log-likelihood, B=512, S=512, T=128.
// ROUND 19: R16 base (205us best; R17 setprio null; R18 single-domain
// regression reverted) + two independent latency fixes:
//  1. BALLOT-PACKED MASK: mk[ss] has a uniform address -> hipcc emits
//     s_load (SMEM), which shares lgkmcnt -> our lgkm barrier was draining
//     a first-touch (HBM ~900cyc) scalar load every group. Now: wave 0
//     packs mask[512] into 8 x u64 in LDS at init (per-lane VMEM +
//     __ballot); per group one uniform ds_read_b64 + u64 shift; per step
//     a 2-VALU bit test. Zero SMEM in the main loop.
//  2. ANTI-PHASE STAGGER: R16's wall 963 ~= 2I+L (I~220 issue, L~450
//     latency) = the two co-resident blocks in symmetric lockstep, both
//     stalling at their barriers simultaneously. Anti-phase gives I+L
//     ~650. Blocks with (blockIdx.x>>8)&1 sleep ~512cyc at start
//     (round-robin fill pairs (b, b+256) on a CU); offset is neutral-
//     stable. No-op if pairing differs.
// Kept from R16 (passed, absmax 0.0): 4 waves/batch, 2 blocks/CU,
// rg=lane&3 (32 rows), 2 cols/lane, 2-stage DPP value-routed reduce,
// normalize every 4th step, lgkm-only barrier, xor-swizzled p double
// buffer (0 conflicts), linear-domain recursion + exact double Ld.

#define T 128
#define SLEN 512
#define BATCH 512

typedef float v2f __attribute__((ext_vector_type(2)));

static __device__ __forceinline__ float dpp_xor1(float x) {
    // quad_perm [1,0,3,2] == lane ^ 1
    return __int_as_float(__builtin_amdgcn_update_dpp(
        0, __float_as_int(x), 0xB1, 0xF, 0xF, true));
}
static __device__ __forceinline__ float dpp_xor2(float x) {
    // quad_perm [2,3,0,1] == lane ^ 2
    return __int_as_float(__builtin_amdgcn_update_dpp(
        0, __float_as_int(x), 0x4E, 0xF, 0xF, true));
}
static __device__ __forceinline__ void lgkm_barrier() {
    // LDS-writes-drained barrier that leaves vmcnt (global prefetch) alone.
    asm volatile("s_waitcnt lgkmcnt(0)\n\ts_barrier" ::: "memory");
}
// Bank swizzle for the 128-word p buffer: 4-word groups xor'd by (j>>5).
static __device__ __forceinline__ int pslot(int j) {
    return j ^ (((j >> 5) & 3) << 2);
}

__global__ __launch_bounds__(256, 2) void fwd_kernel(
    const float* __restrict__ em, const int* __restrict__ tags,
    const int* __restrict__ mask, const float* __restrict__ startT,
    const float* __restrict__ endT, const float* __restrict__ trans,
    float* __restrict__ ws)
{
    const int tid  = threadIdx.x;      // 0..255
    const int lane = tid & 63;
    const int w    = tid >> 6;         // wave 0..3: cols 32w..32w+31
    const int rg   = lane & 3;         // row group: rows 32rg..32rg+31
    const int cg   = lane >> 2;        // col pair within wave: 0..15
    const int b    = blockIdx.x;
    const int rb0  = rg & 1;
    const int colbase = 32 * w + 2 * cg;       // lane's col pair {cb, cb+1}
    const int mycol   = colbase + rb0;         // final owned col (dup x2)

    // Anti-phase stagger: delay the second-slot blocks ~512 cyc.
    if ((blockIdx.x >> 8) & 1) __builtin_amdgcn_s_sleep(8);

    const float* emb = em + (size_t)b * SLEN * T;
    const int*   mk  = mask + (size_t)b * SLEN;

    __shared__ __align__(16) float p_lds[2][T];   // double buffer, 1 KB
    __shared__ float reds[4], redn[4];
    __shared__ int   redc[4];
    __shared__ unsigned long long mbits[8];       // 512 mask bits

    // Read slots: instr k2 reads rows 32rg+4k2..+3 at swizzled slot
    // 32rg + 4*(k2^rg)  [(j>>5)&3 == rg in this range].
    int rslot[8];
#pragma unroll
    for (int k2 = 0; k2 < 8; ++k2)
        rslot[k2] = 32 * rg + 4 * (k2 ^ rg);
    const int wslot = pslot(mycol);

    // Pack mask bits: wave 0 only; per-lane VMEM loads, wave ballot.
    if (w == 0) {
#pragma unroll
        for (int seg = 0; seg < 8; ++seg) {
            const int mval = mk[seg * 64 + lane];
            const unsigned long long bal = __ballot(mval != 0);
            if (lane == 0) mbits[seg] = bal;
        }
    }

    // E fragment: for col c in {0,1} of the pair, rows r = 32rg+4k2:
    // Elo[c][k2] = (e^trans[r][cb+c], e^trans[r+1][cb+c]); Ehi = r+2, r+3.
    // 32 v2f = 64 regs.
    v2f Elo[2][8], Ehi[2][8];
#pragma unroll
    for (int k2 = 0; k2 < 8; ++k2) {
        const float* tp = trans + (32 * rg + 4 * k2) * T + colbase;
#pragma unroll
        for (int c = 0; c < 2; ++c) {
            Elo[c][k2] = (v2f){ __expf(tp[0 * T + c]), __expf(tp[1 * T + c]) };
            Ehi[c][k2] = (v2f){ __expf(tp[2 * T + c]), __expf(tp[3 * T + c]) };
        }
    }

    // alpha_0 in linear domain; step 1 reads buffer 1. Writers rg<2 only
    // (32 distinct banks per wave); all lanes keep pprev (dup x2 over rg>>1).
    float pprev = __expf(startT[mycol] + emb[mycol]);
    if (rg < 2) p_lds[1][wslot] = pprev;
    double Ld = 0.0;

    // 4-deep emission prefetch; exp applied off-chain. (Mask now from LDS
    // ballot words - no SMEM in the loop.)
    float emv[4], emn[4];
#pragma unroll
    for (int k = 0; k < 4; ++k)
        emv[k] = __expf(emb[(1 + k) * T + mycol]);
    lgkm_barrier();   // also publishes mbits[]

    for (int s0 = 1; s0 < SLEN; s0 += 4) {
        // Mask bits for steps s0..s0+3: uniform ds_read_b64 + u64 shift.
        // s0 = 1 mod 4, so (s0&63) <= 61 and bits (s0&63)+k for executed
        // steps (s<SLEN) stay inside the word.
        const unsigned long long mword = mbits[s0 >> 6] >> (s0 & 63);
#pragma unroll
        for (int k = 0; k < 4; ++k) {
            int ss = s0 + 4 + k; ss = (ss < SLEN) ? ss : (SLEN - 1);  // uniform
            emn[k] = emb[ss * T + mycol];
        }
#pragma unroll
        for (int k = 0; k < 4; ++k) {
            const int s = s0 + k;
            if (s < SLEN) {                       // uniform guard (511 steps)
                const int cur = (1 + k) & 1;      // == s&1, compile-time
                const bool mstep = (mword >> k) & 1;   // mask[s] != 0
                // Normalize only on k==0 (s = 1 mod 4): 128 of 511 steps.
                float cc = 1.0f;
                if (k == 0) {
                    const float srefc = fmaxf(p_lds[cur][0], 1e-30f);
                    cc = __builtin_amdgcn_rcpf(srefc);
                    Ld += (double)__logf(srefc);  // exact accounting
                }

                // 8 b128 reads (bank-quads k2^rg: conflict-free; cg bcast).
                v2f pk0[8], pk1[8];
#pragma unroll
                for (int k2 = 0; k2 < 8; ++k2) {
                    const float4 pv = *(const float4*)&p_lds[cur][rslot[k2]];
                    pk0[k2] = (v2f){ pv.x, pv.y };
                    pk1[k2] = (v2f){ pv.z, pv.w };
                }
                // 32 pk_fma in 4 independent depth-8 chains (2 cols x E/O).
                v2f a0e = pk0[0] * Elo[0][0];
                v2f a0o = pk1[0] * Ehi[0][0];
                v2f a1e = pk0[0] * Elo[1][0];
                v2f a1o = pk1[0] * Ehi[1][0];
#pragma unroll
                for (int k2 = 1; k2 < 8; ++k2) {
                    a0e = __builtin_elementwise_fma(pk0[k2], Elo[0][k2], a0e);
                    a0o = __builtin_elementwise_fma(pk1[k2], Ehi[0][k2], a0o);
                    a1e = __builtin_elementwise_fma(pk0[k2], Elo[1][k2], a1e);
                    a1o = __builtin_elementwise_fma(pk1[k2], Ehi[1][k2], a1o);
                }
                const v2f s0v = a0e + a0o, s1v = a1e + a1o;
                const float sv0 = s0v.x + s0v.y;
                const float sv1 = s1v.x + s1v.y;

                // 2-stage DPP value-routed reduce over 4 rg lanes.
                const float v1 = (rb0 ? sv1 : sv0)
                               + dpp_xor1(rb0 ? sv0 : sv1);
                const float t  = v1 + dpp_xor2(v1);

                // Linear-domain update; mask=0 keeps alpha (scaled on
                // normalize steps only).
                float pn, pm;
                if (k == 0) { pn = t * (emv[k] * cc); pm = pprev * cc; }
                else        { pn = t * emv[k];        pm = pprev;      }
                pprev = mstep ? pn : pm;
                if (rg < 2) p_lds[cur ^ 1][wslot] = pprev;
                lgkm_barrier();                   // no vmcnt drain
            }
        }
#pragma unroll
        for (int k = 0; k < 4; ++k) emv[k] = __expf(emn[k]);
    }

    // ---- denominator: log(sum_j p_j e^endT_j) + Ld  (cols dup x2 over
    // rg>>1 -> exact 0.5f fix) ----
    const float eendv = __expf(endT[mycol]);
    float sm = pprev * eendv;
#pragma unroll
    for (int off = 32; off; off >>= 1) sm += __shfl_xor(sm, off);
    if (lane == 0) reds[w] = sm;

    // ---- numerator: 2 strided steps per thread ----
    const int* tg = tags + (size_t)b * SLEN;
    float nv = 0.f; int cnt = 0;
#pragma unroll
    for (int rep = 0; rep < 2; ++rep) {
        const int s = tid + 256 * rep;
        const int mm = mk[s];
        cnt += (mm != 0);
        if (s >= 1 && mm > 0)
            nv += trans[tg[s - 1] * T + tg[s]] + emb[s * T + tg[s]];
    }
#pragma unroll
    for (int off = 32; off; off >>= 1) {
        nv  += __shfl_xor(nv, off);
        cnt += __shfl_xor(cnt, off);
    }
    if (lane == 0) { redn[w] = nv; redc[w] = cnt; }
    __syncthreads();
    if (tid == 0) {
        float ssum = 0.f, nsum = 0.f; int seqlen = 0;
#pragma unroll
        for (int i = 0; i < 4; ++i) {
            ssum += reds[i]; nsum += redn[i]; seqlen += redc[i];
        }
        const float denom = __logf(0.5f * ssum) + (float)Ld;  // exact /2
        const int t0g = tg[0], tl = tg[seqlen - 1];
        ws[b] = (startT[t0g] + emb[t0g] + endT[tl] + nsum) - denom;
    }
}

__global__ __launch_bounds__(256) void reduce_kernel(
    const float* __restrict__ ws, float* __restrict__ out)
{
    const int t = threadIdx.x;          // one block of 256
    float local = 0.f;
    for (int i = t; i < BATCH; i += 256) local += ws[i];
    __shared__ float rf[256];
    rf[t] = local;
    __syncthreads();
    for (int off = 128; off > 0; off >>= 1) {
        if (t < off) rf[t] += rf[t + off];
        __syncthreads();
    }
    if (t == 0) out[0] = rf[0];
}

extern "C" void kernel_launch(void* const* d_in, const int* in_sizes, int n_in,
                              void* d_out, int out_size, void* d_ws, size_t ws_size,
                              hipStream_t stream)
{
    const float* emissions = (const float*)d_in[0];
    const int*   tags      = (const int*)d_in[1];
    const int*   mask      = (const int*)d_in[2];
    const float* startT    = (const float*)d_in[3];
    const float* endT      = (const float*)d_in[4];
    const float* trans     = (const float*)d_in[5];
    float* out = (float*)d_out;
    float* ws  = (float*)d_ws;          // BATCH floats of per-batch partials

    fwd_kernel<<<BATCH, 256, 0, stream>>>(emissions, tags, mask, startT, endT, trans, ws);
    reduce_kernel<<<1, 256, 0, stream>>>(ws, out);
}